// Round 1
// baseline (2582.730 us; speedup 1.0000x reference)
//
#include <hip/hip_runtime.h>
#include <hip/hip_bf16.h>

#define NN 100000
#define EE 1600000
#define MM 20000
#define EPSV 1e-5f

// ---------------- graph kernels ----------------

__global__ void k_count(const int* __restrict__ dst, float* __restrict__ cntf, int E) {
    int e = blockIdx.x * blockDim.x + threadIdx.x;
    if (e < E) atomicAdd(&cntf[dst[e]], 1.0f);
}

__global__ void k_mark(const int* __restrict__ nidx, int* __restrict__ mark, int M) {
    int m = blockIdx.x * blockDim.x + threadIdx.x;
    if (m < M) mark[nidx[m]] = 1;
}

__global__ void k_invcnt(float* __restrict__ cntf, int n) {
    int i = blockIdx.x * blockDim.x + threadIdx.x;
    if (i < n) cntf[i] = 1.0f / fmaxf(cntf[i], 1.0f);
}

// one 64-lane wave per edge; lane handles 2 consecutive floats (float2)
__global__ void k_scatter(const int* __restrict__ src, const int* __restrict__ dst,
                          const float* __restrict__ feat, float* __restrict__ acc,
                          const int* __restrict__ mark, int E) {
    int lane = threadIdx.x & 63;
    int e = blockIdx.x * (blockDim.x >> 6) + (threadIdx.x >> 6);
    if (e >= E) return;
    int d = dst[e];
    if (mark != nullptr && mark[d] == 0) return;   // layer-2: only needed dst nodes
    int s = src[e];
    const float2* xr = (const float2*)(feat + (size_t)s * 128);
    float2 v = xr[lane];
    float* ar = acc + (size_t)d * 128;
    atomicAdd(&ar[lane * 2 + 0], v.x);
    atomicAdd(&ar[lane * 2 + 1], v.y);
}

// ---------------- SAGE dense: out = (aggr*inv)@Wl.T + bl + hin@Wr.T ----------------
// block 256, TR rows per block, 128 output cols; thread computes TR/2 rows x 1 col.
template <int TR>
__global__ void k_sage_dense(const float* __restrict__ aggr, const float* __restrict__ inv_cnt,
                             const float* __restrict__ hin, const int* __restrict__ gather_idx,
                             const float* __restrict__ Wl, const float* __restrict__ bl,
                             const float* __restrict__ Wr, float* __restrict__ hout,
                             int nrows, int do_relu) {
    __shared__ float lds_a[TR][128];
    __shared__ float lds_x[TR][128];
    int t = threadIdx.x;
    int rowBase = blockIdx.x * TR;
    for (int idx = t; idx < TR * 128; idx += 256) {
        int r = idx >> 7, k = idx & 127;
        int grow = rowBase + r;
        float va = 0.f, vx = 0.f;
        if (grow < nrows) {
            int node = gather_idx ? gather_idx[grow] : grow;
            float ic = inv_cnt[node];
            va = aggr[(size_t)node * 128 + k] * ic;
            vx = hin[(size_t)node * 128 + k];
        }
        lds_a[r][k] = va;
        lds_x[r][k] = vx;
    }
    __syncthreads();
    const int RPT = TR / 2;
    int j = t & 127;
    int rg = t >> 7;  // 0 or 1
    float acc[RPT];
    float bj = bl[j];
#pragma unroll
    for (int r = 0; r < RPT; r++) acc[r] = bj;
    const float* wlrow = Wl + j * 128;
    const float* wrrow = Wr + j * 128;
    for (int k = 0; k < 128; k++) {
        float wl = wlrow[k];
        float wr = wrrow[k];
#pragma unroll
        for (int r = 0; r < RPT; r++)
            acc[r] += lds_a[rg * RPT + r][k] * wl + lds_x[rg * RPT + r][k] * wr;
    }
#pragma unroll
    for (int r = 0; r < RPT; r++) {
        int row = rowBase + rg * RPT + r;
        if (row < nrows) {
            float v = acc[r];
            if (do_relu) v = fmaxf(v, 0.f);
            hout[(size_t)row * 128 + j] = v;
        }
    }
}

// ---------------- plain FC: out[OC] = in[128] @ W.T + b ----------------
template <int OC, int TR>
__global__ void k_fc(const float* __restrict__ in, const float* __restrict__ W,
                     const float* __restrict__ b, float* __restrict__ out, int nrows) {
    __shared__ float lds[TR][128];
    int t = threadIdx.x;
    int rowBase = blockIdx.x * TR;
    for (int idx = t; idx < TR * 128; idx += 256) {
        int r = idx >> 7, k = idx & 127;
        int grow = rowBase + r;
        lds[r][k] = (grow < nrows) ? in[(size_t)grow * 128 + k] : 0.f;
    }
    __syncthreads();
    const int GR = 256 / OC;
    const int RPT = TR / GR;
    int j = t % OC;
    int rg = t / OC;
    float acc[RPT];
    float bj = b[j];
#pragma unroll
    for (int r = 0; r < RPT; r++) acc[r] = bj;
    const float* wrow = W + j * 128;
    for (int k = 0; k < 128; k++) {
        float w = wrow[k];
#pragma unroll
        for (int r = 0; r < RPT; r++) acc[r] += lds[rg * RPT + r][k] * w;
    }
#pragma unroll
    for (int r = 0; r < RPT; r++) {
        int row = rowBase + rg * RPT + r;
        if (row < nrows) out[(size_t)row * OC + j] = acc[r];
    }
}

// ---------------- batchnorm stats / prep / apply ----------------
template <int C>
__global__ void k_bnstats(const float* __restrict__ z, float* __restrict__ gsum,
                          float* __restrict__ gsq, int nrows, int rowsPerBlock) {
    int t = threadIdx.x;
    int c = t % C;
    int g = t / C;
    const int G = 256 / C;
    int r0 = blockIdx.x * rowsPerBlock;
    int r1 = min(r0 + rowsPerBlock, nrows);
    float s = 0.f, q = 0.f;
    for (int r = r0 + g; r < r1; r += G) {
        float v = z[(size_t)r * C + c];
        s += v;
        q += v * v;
    }
    __shared__ float ls[256], lq[256];
    ls[t] = s;
    lq[t] = q;
    __syncthreads();
    if (t < C) {
        for (int g2 = 1; g2 < G; g2++) {
            s += ls[g2 * C + c];
            q += lq[g2 * C + c];
        }
        atomicAdd(&gsum[c], s);
        atomicAdd(&gsq[c], q);
    }
}

__global__ void k_bnprep(const float* __restrict__ gsum, const float* __restrict__ gsq,
                         const float* __restrict__ gamma, const float* __restrict__ beta,
                         float* __restrict__ scale, float* __restrict__ shift, int C, float invM) {
    int c = blockIdx.x * blockDim.x + threadIdx.x;
    if (c < C) {
        float mean = gsum[c] * invM;
        float var = gsq[c] * invM - mean * mean;
        float is = rsqrtf(var + EPSV);
        float sc = gamma[c] * is;
        scale[c] = sc;
        shift[c] = beta[c] - mean * sc;
    }
}

__global__ void k_bn_act(float* __restrict__ z, const float* __restrict__ scale,
                         const float* __restrict__ shift, int total, int colsMask, float slope) {
    int i = blockIdx.x * blockDim.x + threadIdx.x;
    if (i < total) {
        int c = i & colsMask;
        float y = z[i] * scale[c] + shift[c];
        z[i] = (y >= 0.f) ? y : slope * y;
    }
}

// ---------------- final fc3: wave per row, 64-dot ----------------
__global__ void k_fc3(const float* __restrict__ z2, const float* __restrict__ w,
                      const float* __restrict__ b, float* __restrict__ out, int nrows) {
    int lane = threadIdx.x & 63;
    int m = blockIdx.x * (blockDim.x >> 6) + (threadIdx.x >> 6);
    if (m >= nrows) return;
    float v = z2[(size_t)m * 64 + lane] * w[lane];
    for (int off = 32; off > 0; off >>= 1) v += __shfl_down(v, off);
    if (lane == 0) out[m] = v + b[0];
}

// ---------------- launch ----------------
extern "C" void kernel_launch(void* const* d_in, const int* in_sizes, int n_in,
                              void* d_out, int out_size, void* d_ws, size_t ws_size,
                              hipStream_t stream) {
    const float* x    = (const float*)d_in[0];
    const int*   ei   = (const int*)d_in[1];
    const int*   nidx = (const int*)d_in[2];
    const float* W1l  = (const float*)d_in[3];
    const float* b1   = (const float*)d_in[4];
    const float* W1r  = (const float*)d_in[5];
    const float* W2l  = (const float*)d_in[6];
    const float* b2   = (const float*)d_in[7];
    const float* W2r  = (const float*)d_in[8];
    const float* fcW1 = (const float*)d_in[9];
    const float* fcb1 = (const float*)d_in[10];
    const float* fcW2 = (const float*)d_in[11];
    const float* fcb2 = (const float*)d_in[12];
    const float* fcW3 = (const float*)d_in[13];
    const float* fcb3 = (const float*)d_in[14];
    const float* g1   = (const float*)d_in[15];
    const float* be1  = (const float*)d_in[16];
    const float* g2   = (const float*)d_in[17];
    const float* be2  = (const float*)d_in[18];

    const int N = in_sizes[0] / 128;
    const int E = in_sizes[1] / 2;
    const int M = in_sizes[2];
    const int* src = ei;
    const int* dst = ei + E;

    char* ws = (char*)d_ws;
    size_t off = 0;
    float* s    = (float*)(ws + off); off += (size_t)N * 128 * 4;   // 51.2 MB
    float* h1   = (float*)(ws + off); off += (size_t)N * 128 * 4;   // 51.2 MB
    float* z0   = (float*)(ws + off); off += (size_t)M * 128 * 4;   // 10.24 MB
    float* z1   = (float*)(ws + off); off += (size_t)M * 128 * 4;   // 10.24 MB
    float* z2   = (float*)(ws + off); off += (size_t)M * 64 * 4;    // 5.12 MB
    float* cntf = (float*)(ws + off); off += (size_t)N * 4;         // 0.4 MB
    int*   mark = (int*)(ws + off);   off += (size_t)N * 4;         // 0.4 MB
    float* gsum1  = (float*)(ws + off); off += 128 * 4;
    float* gsq1   = (float*)(ws + off); off += 128 * 4;
    float* scale1 = (float*)(ws + off); off += 128 * 4;
    float* shift1 = (float*)(ws + off); off += 128 * 4;
    float* gsum2  = (float*)(ws + off); off += 64 * 4;
    float* gsq2   = (float*)(ws + off); off += 64 * 4;
    float* scale2 = (float*)(ws + off); off += 64 * 4;
    float* shift2 = (float*)(ws + off); off += 64 * 4;
    float* out = (float*)d_out;

    // init
    hipMemsetAsync(s, 0, (size_t)N * 128 * 4, stream);
    hipMemsetAsync(cntf, 0, (size_t)N * 4, stream);
    hipMemsetAsync(mark, 0, (size_t)N * 4, stream);
    hipMemsetAsync(gsum1, 0, (128 + 128 + 128 + 128 + 64 + 64 + 64 + 64) * 4, stream);

    k_count<<<(E + 255) / 256, 256, 0, stream>>>(dst, cntf, E);
    k_mark<<<(M + 255) / 256, 256, 0, stream>>>(nidx, mark, M);
    k_invcnt<<<(N + 255) / 256, 256, 0, stream>>>(cntf, N);

    // layer 1
    k_scatter<<<(E + 3) / 4, 256, 0, stream>>>(src, dst, x, s, nullptr, E);
    k_sage_dense<16><<<(N + 15) / 16, 256, 0, stream>>>(s, cntf, x, nullptr, W1l, b1, W1r, h1, N, 1);

    // layer 2 (only dst nodes that feed the output gather)
    hipMemsetAsync(s, 0, (size_t)N * 128 * 4, stream);
    k_scatter<<<(E + 3) / 4, 256, 0, stream>>>(src, dst, h1, s, mark, E);
    k_sage_dense<16><<<(M + 15) / 16, 256, 0, stream>>>(s, cntf, h1, nidx, W2l, b2, W2r, z0, M, 0);

    // MLP head
    k_fc<128, 16><<<(M + 15) / 16, 256, 0, stream>>>(z0, fcW1, fcb1, z1, M);
    k_bnstats<128><<<(M + 99) / 100, 256, 0, stream>>>(z1, gsum1, gsq1, M, 100);
    k_bnprep<<<1, 128, 0, stream>>>(gsum1, gsq1, g1, be1, scale1, shift1, 128, 1.0f / M);
    k_bn_act<<<((size_t)M * 128 + 255) / 256, 256, 0, stream>>>(z1, scale1, shift1, M * 128, 127, 0.1f);

    k_fc<64, 32><<<(M + 31) / 32, 256, 0, stream>>>(z1, fcW2, fcb2, z2, M);
    k_bnstats<64><<<(M + 99) / 100, 256, 0, stream>>>(z2, gsum2, gsq2, M, 100);
    k_bnprep<<<1, 64, 0, stream>>>(gsum2, gsq2, g2, be2, scale2, shift2, 64, 1.0f / M);
    k_bn_act<<<((size_t)M * 64 + 255) / 256, 256, 0, stream>>>(z2, scale2, shift2, M * 64, 63, 0.05f);

    k_fc3<<<(M + 3) / 4, 256, 0, stream>>>(z2, fcW3, fcb3, out, M);
}

// Round 2
// 974.099 us; speedup vs baseline: 2.6514x; 2.6514x over previous
//
#include <hip/hip_runtime.h>
#include <hip/hip_bf16.h>

#define EPSV 1e-5f

// ---------------- CSR build ----------------

__global__ void k_count_i(const int* __restrict__ dst, int* __restrict__ cnt, int E) {
    int e = blockIdx.x * blockDim.x + threadIdx.x;
    if (e < E) atomicAdd(&cnt[dst[e]], 1);
}

// single block, 1024 threads: exclusive scan of cnt -> rowptr, cursor
__global__ void k_scan(const int* __restrict__ cnt, int* __restrict__ rowptr,
                       int* __restrict__ cursor, int n) {
    __shared__ int ls[1024];
    int t = threadIdx.x;
    int chunk = (n + 1023) / 1024;
    int b = t * chunk;
    int e = min(b + chunk, n);
    int s = 0;
    for (int i = b; i < e; i++) s += cnt[i];
    ls[t] = s;
    __syncthreads();
    for (int off = 1; off < 1024; off <<= 1) {
        int v = (t >= off) ? ls[t - off] : 0;
        __syncthreads();
        ls[t] += v;
        __syncthreads();
    }
    int run = ls[t] - s;  // exclusive prefix
    for (int i = b; i < e; i++) {
        rowptr[i] = run;
        cursor[i] = run;
        run += cnt[i];
    }
    if (t == 1023) rowptr[n] = run;
}

__global__ void k_fill(const int* __restrict__ src, const int* __restrict__ dst,
                       int* __restrict__ cursor, int* __restrict__ srclist, int E) {
    int e = blockIdx.x * blockDim.x + threadIdx.x;
    if (e < E) {
        int d = dst[e];
        int pos = atomicAdd(&cursor[d], 1);
        srclist[pos] = src[e];
    }
}

__global__ void k_mark(const int* __restrict__ nidx, int* __restrict__ mark,
                       int* __restrict__ list, int* __restrict__ nmarked, int M) {
    int m = blockIdx.x * blockDim.x + threadIdx.x;
    if (m < M) {
        int n = nidx[m];
        if (atomicExch(&mark[n], 1) == 0) list[atomicAdd(nmarked, 1)] = n;
    }
}

__global__ void k_invcnt(const int* __restrict__ cnt, float* __restrict__ invc, int n) {
    int i = blockIdx.x * blockDim.x + threadIdx.x;
    if (i < n) invc[i] = 1.0f / fmaxf((float)cnt[i], 1.0f);
}

// ---------------- aggregation: wave per dst node, fused mean ----------------
__global__ void k_aggr(const int* __restrict__ rowptr, const int* __restrict__ srclist,
                       const float* __restrict__ feat, const float* __restrict__ invc,
                       const int* __restrict__ list, const int* __restrict__ nlist,
                       float* __restrict__ outf, int n) {
    int lane = threadIdx.x & 63;
    int w = blockIdx.x * (blockDim.x >> 6) + (threadIdx.x >> 6);
    int node;
    if (list) {
        int nm = *nlist;
        if (w >= nm) return;
        node = list[w];
    } else {
        if (w >= n) return;
        node = w;
    }
    int beg = rowptr[node], end = rowptr[node + 1];
    float ax = 0.f, ay = 0.f;
    int i = beg;
    for (; i + 2 <= end; i += 2) {
        int s0 = srclist[i], s1 = srclist[i + 1];
        float2 v0 = *(const float2*)(feat + (size_t)s0 * 128 + lane * 2);
        float2 v1 = *(const float2*)(feat + (size_t)s1 * 128 + lane * 2);
        ax += v0.x + v1.x;
        ay += v0.y + v1.y;
    }
    if (i < end) {
        int s0 = srclist[i];
        float2 v0 = *(const float2*)(feat + (size_t)s0 * 128 + lane * 2);
        ax += v0.x;
        ay += v0.y;
    }
    float ic = invc[node];
    *(float2*)(outf + (size_t)node * 128 + lane * 2) = make_float2(ax * ic, ay * ic);
}

// ---------------- dense: out = A@Wl.T (+ X@Wr.T) + b, optional relu, optional row gather
// KTOT=256: concat [A row | X row]; KTOT=128: A only.
// 256 threads, TR=32 rows/block, thread tile = RPT rows x 4 cols.
template <int KTOT, int OC, int TR>
__global__ void k_dense(const float* __restrict__ A, const float* __restrict__ X,
                        const int* __restrict__ gidx,
                        const float* __restrict__ Wl, const float* __restrict__ bl,
                        const float* __restrict__ Wr,
                        float* __restrict__ out, int nrows, int relu) {
    __shared__ float in_s[TR][KTOT + 4];
    __shared__ float w_s[32][130];
    const int CW = (OC == 128) ? 32 : 16;   // col groups; cols j = tc + c*CW, c=0..3
    const int RPT = TR / (256 / CW);        // OC=128 -> 4 rows, OC=64 -> 2 rows
    int t = threadIdx.x;
    int rowBase = blockIdx.x * TR;

    // stage input tile (float4)
    const int Q = KTOT / 4;
    for (int idx = t; idx < TR * Q; idx += 256) {
        int r = idx / Q, q = idx % Q;
        int grow = rowBase + r;
        float4 v = make_float4(0.f, 0.f, 0.f, 0.f);
        if (grow < nrows) {
            int node = gidx ? gidx[grow] : grow;
            const float* p;
            if (KTOT == 256)
                p = (q < 32) ? (A + (size_t)node * 128 + q * 4)
                             : (X + (size_t)node * 128 + (q - 32) * 4);
            else
                p = A + (size_t)node * 128 + q * 4;
            v = *(const float4*)p;
        }
        *(float4*)&in_s[r][q * 4] = v;
    }

    int tc = t % CW;
    int trg = t / CW;
    float acc[RPT][4];
#pragma unroll
    for (int r = 0; r < RPT; r++)
#pragma unroll
        for (int c = 0; c < 4; c++) acc[r][c] = 0.f;

    const int NCH = KTOT / 32;
    const int NCHL = (KTOT == 256) ? 4 : NCH;  // chunks belonging to Wl
    for (int ch = 0; ch < NCH; ch++) {
        const float* W = (ch < NCHL) ? Wl : Wr;
        int k0 = (ch < NCHL) ? ch * 32 : (ch - NCHL) * 32;
        __syncthreads();
        // stage transposed weight chunk: w_s[kk][j] = W[j][k0+kk]
        for (int idx = t; idx < OC * 8; idx += 256) {
            int j = idx / 8, q4 = idx % 8;
            float4 v = *(const float4*)&W[j * 128 + k0 + q4 * 4];
            w_s[q4 * 4 + 0][j] = v.x;
            w_s[q4 * 4 + 1][j] = v.y;
            w_s[q4 * 4 + 2][j] = v.z;
            w_s[q4 * 4 + 3][j] = v.w;
        }
        __syncthreads();
        int kb = ch * 32;
#pragma unroll
        for (int kk = 0; kk < 32; kk += 4) {
            float ivr[RPT][4];
#pragma unroll
            for (int r = 0; r < RPT; r++) {
                float4 tmp = *(const float4*)&in_s[trg * RPT + r][kb + kk];
                ivr[r][0] = tmp.x; ivr[r][1] = tmp.y; ivr[r][2] = tmp.z; ivr[r][3] = tmp.w;
            }
#pragma unroll
            for (int u = 0; u < 4; u++) {
                float w0 = w_s[kk + u][tc];
                float w1 = w_s[kk + u][tc + CW];
                float w2 = w_s[kk + u][tc + 2 * CW];
                float w3 = w_s[kk + u][tc + 3 * CW];
#pragma unroll
                for (int r = 0; r < RPT; r++) {
                    acc[r][0] += ivr[r][u] * w0;
                    acc[r][1] += ivr[r][u] * w1;
                    acc[r][2] += ivr[r][u] * w2;
                    acc[r][3] += ivr[r][u] * w3;
                }
            }
        }
    }
#pragma unroll
    for (int c = 0; c < 4; c++) {
        int j = tc + c * CW;
        float bj = bl[j];
#pragma unroll
        for (int r = 0; r < RPT; r++) {
            int row = rowBase + trg * RPT + r;
            if (row < nrows) {
                float v = acc[r][c] + bj;
                if (relu) v = fmaxf(v, 0.f);
                out[(size_t)row * OC + j] = v;
            }
        }
    }
}

// ---------------- batchnorm ----------------
template <int C>
__global__ void k_bnstats(const float* __restrict__ z, float* __restrict__ gsum,
                          float* __restrict__ gsq, int nrows, int rowsPerBlock) {
    int t = threadIdx.x;
    int c = t % C;
    int g = t / C;
    const int G = 256 / C;
    int r0 = blockIdx.x * rowsPerBlock;
    int r1 = min(r0 + rowsPerBlock, nrows);
    float s = 0.f, q = 0.f;
    for (int r = r0 + g; r < r1; r += G) {
        float v = z[(size_t)r * C + c];
        s += v;
        q += v * v;
    }
    __shared__ float ls[256], lq[256];
    ls[t] = s;
    lq[t] = q;
    __syncthreads();
    if (t < C) {
        for (int g2 = 1; g2 < G; g2++) {
            s += ls[g2 * C + c];
            q += lq[g2 * C + c];
        }
        atomicAdd(&gsum[c], s);
        atomicAdd(&gsq[c], q);
    }
}

__global__ void k_bnprep(const float* __restrict__ gsum, const float* __restrict__ gsq,
                         const float* __restrict__ gamma, const float* __restrict__ beta,
                         float* __restrict__ scale, float* __restrict__ shift, int C, float invM) {
    int c = blockIdx.x * blockDim.x + threadIdx.x;
    if (c < C) {
        float mean = gsum[c] * invM;
        float var = gsq[c] * invM - mean * mean;
        float is = rsqrtf(var + EPSV);
        float sc = gamma[c] * is;
        scale[c] = sc;
        shift[c] = beta[c] - mean * sc;
    }
}

__global__ void k_bn_act(float* __restrict__ z, const float* __restrict__ scale,
                         const float* __restrict__ shift, int total, int colsMask, float slope) {
    int i = blockIdx.x * blockDim.x + threadIdx.x;
    if (i < total) {
        int c = i & colsMask;
        float y = z[i] * scale[c] + shift[c];
        z[i] = (y >= 0.f) ? y : slope * y;
    }
}

// ---------------- final fc3: wave per row ----------------
__global__ void k_fc3(const float* __restrict__ z2, const float* __restrict__ w,
                      const float* __restrict__ b, float* __restrict__ out, int nrows) {
    int lane = threadIdx.x & 63;
    int m = blockIdx.x * (blockDim.x >> 6) + (threadIdx.x >> 6);
    if (m >= nrows) return;
    float v = z2[(size_t)m * 64 + lane] * w[lane];
    for (int off = 32; off > 0; off >>= 1) v += __shfl_down(v, off);
    if (lane == 0) out[m] = v + b[0];
}

// ---------------- launch ----------------
extern "C" void kernel_launch(void* const* d_in, const int* in_sizes, int n_in,
                              void* d_out, int out_size, void* d_ws, size_t ws_size,
                              hipStream_t stream) {
    const float* x    = (const float*)d_in[0];
    const int*   ei   = (const int*)d_in[1];
    const int*   nidx = (const int*)d_in[2];
    const float* W1l  = (const float*)d_in[3];
    const float* b1   = (const float*)d_in[4];
    const float* W1r  = (const float*)d_in[5];
    const float* W2l  = (const float*)d_in[6];
    const float* b2   = (const float*)d_in[7];
    const float* W2r  = (const float*)d_in[8];
    const float* fcW1 = (const float*)d_in[9];
    const float* fcb1 = (const float*)d_in[10];
    const float* fcW2 = (const float*)d_in[11];
    const float* fcb2 = (const float*)d_in[12];
    const float* fcW3 = (const float*)d_in[13];
    const float* fcb3 = (const float*)d_in[14];
    const float* g1   = (const float*)d_in[15];
    const float* be1  = (const float*)d_in[16];
    const float* g2   = (const float*)d_in[17];
    const float* be2  = (const float*)d_in[18];

    const int N = in_sizes[0] / 128;
    const int E = in_sizes[1] / 2;
    const int M = in_sizes[2];
    const int* src = ei;
    const int* dst = ei + E;

    char* ws = (char*)d_ws;
    size_t off = 0;
    float* s     = (float*)(ws + off); off += (size_t)N * 128 * 4;
    float* h1    = (float*)(ws + off); off += (size_t)N * 128 * 4;
    float* z0    = (float*)(ws + off); off += (size_t)M * 128 * 4;
    float* z1    = (float*)(ws + off); off += (size_t)M * 128 * 4;
    float* z2    = (float*)(ws + off); off += (size_t)M * 64 * 4;
    int*   cnt     = (int*)(ws + off);   off += (size_t)N * 4;
    float* invc    = (float*)(ws + off); off += (size_t)N * 4;
    int*   mark    = (int*)(ws + off);   off += (size_t)N * 4;
    int*   rowptr  = (int*)(ws + off);   off += (size_t)(N + 1) * 4;
    int*   cursor  = (int*)(ws + off);   off += (size_t)N * 4;
    int*   srclist = (int*)(ws + off);   off += (size_t)E * 4;
    int*   list    = (int*)(ws + off);   off += (size_t)M * 4;
    int*   nmarked = (int*)(ws + off);   off += 64;  // keep alignment
    float* gsum1   = (float*)(ws + off); off += 128 * 4;
    float* gsq1    = (float*)(ws + off); off += 128 * 4;
    float* scale1  = (float*)(ws + off); off += 128 * 4;
    float* shift1  = (float*)(ws + off); off += 128 * 4;
    float* gsum2   = (float*)(ws + off); off += 64 * 4;
    float* gsq2    = (float*)(ws + off); off += 64 * 4;
    float* scale2  = (float*)(ws + off); off += 64 * 4;
    float* shift2  = (float*)(ws + off); off += 64 * 4;
    float* out = (float*)d_out;

    // init small buffers only (feature buffers are fully written before read)
    hipMemsetAsync(cnt, 0, (size_t)N * 4, stream);
    hipMemsetAsync(mark, 0, (size_t)N * 4, stream);
    hipMemsetAsync(nmarked, 0, 4, stream);
    hipMemsetAsync(gsum1, 0, (128 + 128 + 128 + 128 + 64 + 64 + 64 + 64) * 4, stream);

    // CSR build (shared by both layers)
    k_count_i<<<(E + 255) / 256, 256, 0, stream>>>(dst, cnt, E);
    k_scan<<<1, 1024, 0, stream>>>(cnt, rowptr, cursor, N);
    k_fill<<<(E + 255) / 256, 256, 0, stream>>>(src, dst, cursor, srclist, E);
    k_mark<<<(M + 255) / 256, 256, 0, stream>>>(nidx, mark, list, nmarked, M);
    k_invcnt<<<(N + 255) / 256, 256, 0, stream>>>(cnt, invc, N);

    // layer 1: aggregate all nodes, dense over all nodes
    k_aggr<<<(N + 3) / 4, 256, 0, stream>>>(rowptr, srclist, x, invc, nullptr, nullptr, s, N);
    k_dense<256, 128, 32><<<(N + 31) / 32, 256, 0, stream>>>(s, x, nullptr, W1l, b1, W1r, h1, N, 1);

    // layer 2: aggregate only marked (needed) nodes, dense over gathered rows
    k_aggr<<<(M + 3) / 4, 256, 0, stream>>>(rowptr, srclist, h1, invc, list, nmarked, s, N);
    k_dense<256, 128, 32><<<(M + 31) / 32, 256, 0, stream>>>(s, h1, nidx, W2l, b2, W2r, z0, M, 0);

    // MLP head
    k_dense<128, 128, 32><<<(M + 31) / 32, 256, 0, stream>>>(z0, nullptr, nullptr, fcW1, fcb1, nullptr, z1, M, 0);
    k_bnstats<128><<<(M + 99) / 100, 256, 0, stream>>>(z1, gsum1, gsq1, M, 100);
    k_bnprep<<<1, 128, 0, stream>>>(gsum1, gsq1, g1, be1, scale1, shift1, 128, 1.0f / M);
    k_bn_act<<<((size_t)M * 128 + 255) / 256, 256, 0, stream>>>(z1, scale1, shift1, M * 128, 127, 0.1f);

    k_dense<128, 64, 32><<<(M + 31) / 32, 256, 0, stream>>>(z1, nullptr, nullptr, fcW2, fcb2, nullptr, z2, M, 0);
    k_bnstats<64><<<(M + 99) / 100, 256, 0, stream>>>(z2, gsum2, gsq2, M, 100);
    k_bnprep<<<1, 64, 0, stream>>>(gsum2, gsq2, g2, be2, scale2, shift2, 64, 1.0f / M);
    k_bn_act<<<((size_t)M * 64 + 255) / 256, 256, 0, stream>>>(z2, scale2, shift2, M * 64, 63, 0.05f);

    k_fc3<<<(M + 3) / 4, 256, 0, stream>>>(z2, fcW3, fcb3, out, M);
}

// Round 3
// 750.096 us; speedup vs baseline: 3.4432x; 1.2986x over previous
//
#include <hip/hip_runtime.h>
#include <hip/hip_bf16.h>

#define EPSV 1e-5f
#define SEG 512

// ---------------- CSR build ----------------

__global__ void k_count_i(const int* __restrict__ dst, int* __restrict__ cnt, int E) {
    int e = blockIdx.x * blockDim.x + threadIdx.x;
    if (e < E) atomicAdd(&cnt[dst[e]], 1);
}

// pass A: per-block (512-seg) sums
__global__ void k_bsum(const int* __restrict__ cnt, int* __restrict__ bsum, int n) {
    __shared__ int ls[256];
    int t = threadIdx.x;
    int base = blockIdx.x * SEG;
    int v = 0;
    int i0 = base + t, i1 = base + 256 + t;
    if (i0 < n) v += cnt[i0];
    if (i1 < n) v += cnt[i1];
    ls[t] = v;
    __syncthreads();
    for (int off = 128; off > 0; off >>= 1) {
        if (t < off) ls[t] += ls[t + off];
        __syncthreads();
    }
    if (t == 0) bsum[blockIdx.x] = ls[0];
}

// pass B: single block exclusive scan of B (<256) block sums
__global__ void k_scanb(int* __restrict__ bsum, int B) {
    __shared__ int ls[256];
    int t = threadIdx.x;
    int v = (t < B) ? bsum[t] : 0;
    ls[t] = v;
    __syncthreads();
    for (int off = 1; off < 256; off <<= 1) {
        int u = (t >= off) ? ls[t - off] : 0;
        __syncthreads();
        ls[t] += u;
        __syncthreads();
    }
    if (t < B) bsum[t] = ls[t] - v;  // exclusive
}

// pass C: per-block scan of 512 cnt entries + global offset -> rowptr/cursor; fused invc
__global__ void k_scanseg(const int* __restrict__ cnt, const int* __restrict__ boff,
                          int* __restrict__ rowptr, int* __restrict__ cursor,
                          float* __restrict__ invc, int n, int B) {
    __shared__ int ls[256];
    int t = threadIdx.x;
    int base = blockIdx.x * SEG;
    int i0 = base + 2 * t, i1 = i0 + 1;
    int c0 = (i0 < n) ? cnt[i0] : 0;
    int c1 = (i1 < n) ? cnt[i1] : 0;
    int ts = c0 + c1;
    ls[t] = ts;
    __syncthreads();
    for (int off = 1; off < 256; off <<= 1) {
        int u = (t >= off) ? ls[t - off] : 0;
        __syncthreads();
        ls[t] += u;
        __syncthreads();
    }
    int ex = ls[t] - ts;  // exclusive prefix of this thread's pair within block
    int gb = boff[blockIdx.x];
    int p0 = gb + ex, p1 = p0 + c0;
    if (i0 < n) {
        rowptr[i0] = p0; cursor[i0] = p0;
        invc[i0] = 1.0f / fmaxf((float)c0, 1.0f);
    }
    if (i1 < n) {
        rowptr[i1] = p1; cursor[i1] = p1;
        invc[i1] = 1.0f / fmaxf((float)c1, 1.0f);
    }
    if (blockIdx.x == B - 1 && t == 255) rowptr[n] = gb + ls[255];
}

__global__ void k_fill(const int* __restrict__ src, const int* __restrict__ dst,
                       int* __restrict__ cursor, int* __restrict__ srclist, int E) {
    int e = blockIdx.x * blockDim.x + threadIdx.x;
    if (e < E) {
        int d = dst[e];
        int pos = atomicAdd(&cursor[d], 1);
        srclist[pos] = src[e];
    }
}

__global__ void k_mark(const int* __restrict__ nidx, int* __restrict__ mark,
                       int* __restrict__ list, int* __restrict__ nmarked, int M) {
    int m = blockIdx.x * blockDim.x + threadIdx.x;
    if (m < M) {
        int n = nidx[m];
        if (atomicExch(&mark[n], 1) == 0) list[atomicAdd(nmarked, 1)] = n;
    }
}

// ---------------- aggregation: wave per dst node, fused mean ----------------
__global__ void k_aggr(const int* __restrict__ rowptr, const int* __restrict__ srclist,
                       const float* __restrict__ feat, const float* __restrict__ invc,
                       const int* __restrict__ list, const int* __restrict__ nlist,
                       float* __restrict__ outf, int n) {
    int lane = threadIdx.x & 63;
    int w = blockIdx.x * (blockDim.x >> 6) + (threadIdx.x >> 6);
    int node;
    if (list) {
        int nm = *nlist;
        if (w >= nm) return;
        node = list[w];
    } else {
        if (w >= n) return;
        node = w;
    }
    int beg = rowptr[node], end = rowptr[node + 1];
    float ax = 0.f, ay = 0.f;
    int i = beg;
    for (; i + 2 <= end; i += 2) {
        int s0 = srclist[i], s1 = srclist[i + 1];
        float2 v0 = *(const float2*)(feat + (size_t)s0 * 128 + lane * 2);
        float2 v1 = *(const float2*)(feat + (size_t)s1 * 128 + lane * 2);
        ax += v0.x + v1.x;
        ay += v0.y + v1.y;
    }
    if (i < end) {
        int s0 = srclist[i];
        float2 v0 = *(const float2*)(feat + (size_t)s0 * 128 + lane * 2);
        ax += v0.x;
        ay += v0.y;
    }
    float ic = invc[node];
    *(float2*)(outf + (size_t)node * 128 + lane * 2) = make_float2(ax * ic, ay * ic);
}

// ---------------- dense: out = A@Wl.T (+ X@Wr.T) + b, optional relu, optional row gather
template <int KTOT, int OC, int TR>
__global__ void k_dense(const float* __restrict__ A, const float* __restrict__ X,
                        const int* __restrict__ gidx,
                        const float* __restrict__ Wl, const float* __restrict__ bl,
                        const float* __restrict__ Wr,
                        float* __restrict__ out, int nrows, int relu) {
    __shared__ float in_s[TR][KTOT + 4];
    __shared__ float w_s[32][130];
    const int CW = (OC == 128) ? 32 : 16;
    const int RPT = TR / (256 / CW);
    int t = threadIdx.x;
    int rowBase = blockIdx.x * TR;

    const int Q = KTOT / 4;
    for (int idx = t; idx < TR * Q; idx += 256) {
        int r = idx / Q, q = idx % Q;
        int grow = rowBase + r;
        float4 v = make_float4(0.f, 0.f, 0.f, 0.f);
        if (grow < nrows) {
            int node = gidx ? gidx[grow] : grow;
            const float* p;
            if (KTOT == 256)
                p = (q < 32) ? (A + (size_t)node * 128 + q * 4)
                             : (X + (size_t)node * 128 + (q - 32) * 4);
            else
                p = A + (size_t)node * 128 + q * 4;
            v = *(const float4*)p;
        }
        *(float4*)&in_s[r][q * 4] = v;
    }

    int tc = t % CW;
    int trg = t / CW;
    float acc[RPT][4];
#pragma unroll
    for (int r = 0; r < RPT; r++)
#pragma unroll
        for (int c = 0; c < 4; c++) acc[r][c] = 0.f;

    const int NCH = KTOT / 32;
    const int NCHL = (KTOT == 256) ? 4 : NCH;
    for (int ch = 0; ch < NCH; ch++) {
        const float* W = (ch < NCHL) ? Wl : Wr;
        int k0 = (ch < NCHL) ? ch * 32 : (ch - NCHL) * 32;
        __syncthreads();
        for (int idx = t; idx < OC * 8; idx += 256) {
            int j = idx / 8, q4 = idx % 8;
            float4 v = *(const float4*)&W[j * 128 + k0 + q4 * 4];
            w_s[q4 * 4 + 0][j] = v.x;
            w_s[q4 * 4 + 1][j] = v.y;
            w_s[q4 * 4 + 2][j] = v.z;
            w_s[q4 * 4 + 3][j] = v.w;
        }
        __syncthreads();
        int kb = ch * 32;
#pragma unroll
        for (int kk = 0; kk < 32; kk += 4) {
            float ivr[RPT][4];
#pragma unroll
            for (int r = 0; r < RPT; r++) {
                float4 tmp = *(const float4*)&in_s[trg * RPT + r][kb + kk];
                ivr[r][0] = tmp.x; ivr[r][1] = tmp.y; ivr[r][2] = tmp.z; ivr[r][3] = tmp.w;
            }
#pragma unroll
            for (int u = 0; u < 4; u++) {
                float w0 = w_s[kk + u][tc];
                float w1 = w_s[kk + u][tc + CW];
                float w2 = w_s[kk + u][tc + 2 * CW];
                float w3 = w_s[kk + u][tc + 3 * CW];
#pragma unroll
                for (int r = 0; r < RPT; r++) {
                    acc[r][0] += ivr[r][u] * w0;
                    acc[r][1] += ivr[r][u] * w1;
                    acc[r][2] += ivr[r][u] * w2;
                    acc[r][3] += ivr[r][u] * w3;
                }
            }
        }
    }
#pragma unroll
    for (int c = 0; c < 4; c++) {
        int j = tc + c * CW;
        float bj = bl[j];
#pragma unroll
        for (int r = 0; r < RPT; r++) {
            int row = rowBase + trg * RPT + r;
            if (row < nrows) {
                float v = acc[r][c] + bj;
                if (relu) v = fmaxf(v, 0.f);
                out[(size_t)row * OC + j] = v;
            }
        }
    }
}

// ---------------- batchnorm ----------------
template <int C>
__global__ void k_bnstats(const float* __restrict__ z, float* __restrict__ gsum,
                          float* __restrict__ gsq, int nrows, int rowsPerBlock) {
    int t = threadIdx.x;
    int c = t % C;
    int g = t / C;
    const int G = 256 / C;
    int r0 = blockIdx.x * rowsPerBlock;
    int r1 = min(r0 + rowsPerBlock, nrows);
    float s = 0.f, q = 0.f;
    for (int r = r0 + g; r < r1; r += G) {
        float v = z[(size_t)r * C + c];
        s += v;
        q += v * v;
    }
    __shared__ float ls[256], lq[256];
    ls[t] = s;
    lq[t] = q;
    __syncthreads();
    if (t < C) {
        for (int g2 = 1; g2 < G; g2++) {
            s += ls[g2 * C + c];
            q += lq[g2 * C + c];
        }
        atomicAdd(&gsum[c], s);
        atomicAdd(&gsq[c], q);
    }
}

__global__ void k_bnprep(const float* __restrict__ gsum, const float* __restrict__ gsq,
                         const float* __restrict__ gamma, const float* __restrict__ beta,
                         float* __restrict__ scale, float* __restrict__ shift, int C, float invM) {
    int c = blockIdx.x * blockDim.x + threadIdx.x;
    if (c < C) {
        float mean = gsum[c] * invM;
        float var = gsq[c] * invM - mean * mean;
        float is = rsqrtf(var + EPSV);
        float sc = gamma[c] * is;
        scale[c] = sc;
        shift[c] = beta[c] - mean * sc;
    }
}

__global__ void k_bn_act(float* __restrict__ z, const float* __restrict__ scale,
                         const float* __restrict__ shift, int total, int colsMask, float slope) {
    int i = blockIdx.x * blockDim.x + threadIdx.x;
    if (i < total) {
        int c = i & colsMask;
        float y = z[i] * scale[c] + shift[c];
        z[i] = (y >= 0.f) ? y : slope * y;
    }
}

// ---------------- final fc3: wave per row ----------------
__global__ void k_fc3(const float* __restrict__ z2, const float* __restrict__ w,
                      const float* __restrict__ b, float* __restrict__ out, int nrows) {
    int lane = threadIdx.x & 63;
    int m = blockIdx.x * (blockDim.x >> 6) + (threadIdx.x >> 6);
    if (m >= nrows) return;
    float v = z2[(size_t)m * 64 + lane] * w[lane];
    for (int off = 32; off > 0; off >>= 1) v += __shfl_down(v, off);
    if (lane == 0) out[m] = v + b[0];
}

// ---------------- launch ----------------
extern "C" void kernel_launch(void* const* d_in, const int* in_sizes, int n_in,
                              void* d_out, int out_size, void* d_ws, size_t ws_size,
                              hipStream_t stream) {
    const float* x    = (const float*)d_in[0];
    const int*   ei   = (const int*)d_in[1];
    const int*   nidx = (const int*)d_in[2];
    const float* W1l  = (const float*)d_in[3];
    const float* b1   = (const float*)d_in[4];
    const float* W1r  = (const float*)d_in[5];
    const float* W2l  = (const float*)d_in[6];
    const float* b2   = (const float*)d_in[7];
    const float* W2r  = (const float*)d_in[8];
    const float* fcW1 = (const float*)d_in[9];
    const float* fcb1 = (const float*)d_in[10];
    const float* fcW2 = (const float*)d_in[11];
    const float* fcb2 = (const float*)d_in[12];
    const float* fcW3 = (const float*)d_in[13];
    const float* fcb3 = (const float*)d_in[14];
    const float* g1   = (const float*)d_in[15];
    const float* be1  = (const float*)d_in[16];
    const float* g2   = (const float*)d_in[17];
    const float* be2  = (const float*)d_in[18];

    const int N = in_sizes[0] / 128;
    const int E = in_sizes[1] / 2;
    const int M = in_sizes[2];
    const int* src = ei;
    const int* dst = ei + E;
    const int B = (N + SEG - 1) / SEG;  // scan blocks (196 for N=100k, must be <=256)

    char* ws = (char*)d_ws;
    size_t off = 0;
    float* s     = (float*)(ws + off); off += (size_t)N * 128 * 4;
    float* h1    = (float*)(ws + off); off += (size_t)N * 128 * 4;
    float* z0    = (float*)(ws + off); off += (size_t)M * 128 * 4;
    float* z1    = (float*)(ws + off); off += (size_t)M * 128 * 4;
    float* z2    = (float*)(ws + off); off += (size_t)M * 64 * 4;
    int*   cnt     = (int*)(ws + off);   off += (size_t)N * 4;
    float* invc    = (float*)(ws + off); off += (size_t)N * 4;
    int*   mark    = (int*)(ws + off);   off += (size_t)N * 4;
    int*   rowptr  = (int*)(ws + off);   off += (size_t)(N + 1) * 4;
    int*   cursor  = (int*)(ws + off);   off += (size_t)N * 4;
    int*   srclist = (int*)(ws + off);   off += (size_t)E * 4;
    int*   list    = (int*)(ws + off);   off += (size_t)M * 4;
    int*   bsum    = (int*)(ws + off);   off += 256 * 4;
    int*   nmarked = (int*)(ws + off);   off += 64;
    float* gsum1   = (float*)(ws + off); off += 128 * 4;
    float* gsq1    = (float*)(ws + off); off += 128 * 4;
    float* scale1  = (float*)(ws + off); off += 128 * 4;
    float* shift1  = (float*)(ws + off); off += 128 * 4;
    float* gsum2   = (float*)(ws + off); off += 64 * 4;
    float* gsq2    = (float*)(ws + off); off += 64 * 4;
    float* scale2  = (float*)(ws + off); off += 64 * 4;
    float* shift2  = (float*)(ws + off); off += 64 * 4;
    float* out = (float*)d_out;

    hipMemsetAsync(cnt, 0, (size_t)N * 4, stream);
    hipMemsetAsync(mark, 0, (size_t)N * 4, stream);
    hipMemsetAsync(nmarked, 0, 4, stream);
    hipMemsetAsync(gsum1, 0, (128 + 128 + 128 + 128 + 64 + 64 + 64 + 64) * 4, stream);

    // CSR build (parallel scan)
    k_count_i<<<(E + 255) / 256, 256, 0, stream>>>(dst, cnt, E);
    k_bsum<<<B, 256, 0, stream>>>(cnt, bsum, N);
    k_scanb<<<1, 256, 0, stream>>>(bsum, B);
    k_scanseg<<<B, 256, 0, stream>>>(cnt, bsum, rowptr, cursor, invc, N, B);
    k_fill<<<(E + 255) / 256, 256, 0, stream>>>(src, dst, cursor, srclist, E);
    k_mark<<<(M + 255) / 256, 256, 0, stream>>>(nidx, mark, list, nmarked, M);

    // layer 1
    k_aggr<<<(N + 3) / 4, 256, 0, stream>>>(rowptr, srclist, x, invc, nullptr, nullptr, s, N);
    k_dense<256, 128, 32><<<(N + 31) / 32, 256, 0, stream>>>(s, x, nullptr, W1l, b1, W1r, h1, N, 1);

    // layer 2 (only marked dst nodes)
    k_aggr<<<(M + 3) / 4, 256, 0, stream>>>(rowptr, srclist, h1, invc, list, nmarked, s, N);
    k_dense<256, 128, 32><<<(M + 31) / 32, 256, 0, stream>>>(s, h1, nidx, W2l, b2, W2r, z0, M, 0);

    // MLP head
    k_dense<128, 128, 32><<<(M + 31) / 32, 256, 0, stream>>>(z0, nullptr, nullptr, fcW1, fcb1, nullptr, z1, M, 0);
    k_bnstats<128><<<(M + 99) / 100, 256, 0, stream>>>(z1, gsum1, gsq1, M, 100);
    k_bnprep<<<1, 128, 0, stream>>>(gsum1, gsq1, g1, be1, scale1, shift1, 128, 1.0f / M);
    k_bn_act<<<((size_t)M * 128 + 255) / 256, 256, 0, stream>>>(z1, scale1, shift1, M * 128, 127, 0.1f);

    k_dense<128, 64, 32><<<(M + 31) / 32, 256, 0, stream>>>(z1, fcW2 ? nullptr : nullptr, nullptr, fcW2, fcb2, nullptr, z2, M, 0);
    k_bnstats<64><<<(M + 99) / 100, 256, 0, stream>>>(z2, gsum2, gsq2, M, 100);
    k_bnprep<<<1, 64, 0, stream>>>(gsum2, gsq2, g2, be2, scale2, shift2, 64, 1.0f / M);
    k_bn_act<<<((size_t)M * 64 + 255) / 256, 256, 0, stream>>>(z2, scale2, shift2, M * 64, 63, 0.05f);

    k_fc3<<<(M + 3) / 4, 256, 0, stream>>>(z2, fcW3, fcb3, out, M);
}

// Round 4
// 556.652 us; speedup vs baseline: 4.6398x; 1.3475x over previous
//
#include <hip/hip_runtime.h>
#include <hip/hip_bf16.h>

#define EPSV 1e-5f
#define SEG 512

typedef __attribute__((ext_vector_type(8))) short s16x8;
typedef __attribute__((ext_vector_type(4))) float f32x4;

static __device__ __forceinline__ unsigned short f2b(float f) {
    __hip_bfloat16 h = __float2bfloat16(f);
    return *reinterpret_cast<unsigned short*>(&h);
}

// ---------------- CSR build ----------------

__global__ void k_count_i(const int* __restrict__ dst, int* __restrict__ cnt, int E) {
    int e = blockIdx.x * blockDim.x + threadIdx.x;
    if (e < E) atomicAdd(&cnt[dst[e]], 1);
}

__global__ void k_bsum(const int* __restrict__ cnt, int* __restrict__ bsum, int n) {
    __shared__ int ls[256];
    int t = threadIdx.x;
    int base = blockIdx.x * SEG;
    int v = 0;
    int i0 = base + t, i1 = base + 256 + t;
    if (i0 < n) v += cnt[i0];
    if (i1 < n) v += cnt[i1];
    ls[t] = v;
    __syncthreads();
    for (int off = 128; off > 0; off >>= 1) {
        if (t < off) ls[t] += ls[t + off];
        __syncthreads();
    }
    if (t == 0) bsum[blockIdx.x] = ls[0];
}

__global__ void k_scanb(int* __restrict__ bsum, int B) {
    __shared__ int ls[256];
    int t = threadIdx.x;
    int v = (t < B) ? bsum[t] : 0;
    ls[t] = v;
    __syncthreads();
    for (int off = 1; off < 256; off <<= 1) {
        int u = (t >= off) ? ls[t - off] : 0;
        __syncthreads();
        ls[t] += u;
        __syncthreads();
    }
    if (t < B) bsum[t] = ls[t] - v;
}

__global__ void k_scanseg(const int* __restrict__ cnt, const int* __restrict__ boff,
                          int* __restrict__ rowptr, int* __restrict__ cursor,
                          float* __restrict__ invc, int n, int B) {
    __shared__ int ls[256];
    int t = threadIdx.x;
    int base = blockIdx.x * SEG;
    int i0 = base + 2 * t, i1 = i0 + 1;
    int c0 = (i0 < n) ? cnt[i0] : 0;
    int c1 = (i1 < n) ? cnt[i1] : 0;
    int ts = c0 + c1;
    ls[t] = ts;
    __syncthreads();
    for (int off = 1; off < 256; off <<= 1) {
        int u = (t >= off) ? ls[t - off] : 0;
        __syncthreads();
        ls[t] += u;
        __syncthreads();
    }
    int ex = ls[t] - ts;
    int gb = boff[blockIdx.x];
    int p0 = gb + ex, p1 = p0 + c0;
    if (i0 < n) {
        rowptr[i0] = p0; cursor[i0] = p0;
        invc[i0] = 1.0f / fmaxf((float)c0, 1.0f);
    }
    if (i1 < n) {
        rowptr[i1] = p1; cursor[i1] = p1;
        invc[i1] = 1.0f / fmaxf((float)c1, 1.0f);
    }
    if (blockIdx.x == B - 1 && t == 255) rowptr[n] = gb + ls[255];
}

__global__ void k_fill(const int* __restrict__ src, const int* __restrict__ dst,
                       int* __restrict__ cursor, int* __restrict__ srclist, int E) {
    int e = blockIdx.x * blockDim.x + threadIdx.x;
    if (e < E) {
        int d = dst[e];
        int pos = atomicAdd(&cursor[d], 1);
        srclist[pos] = src[e];
    }
}

__global__ void k_mark(const int* __restrict__ nidx, int* __restrict__ mark,
                       int* __restrict__ list, int* __restrict__ nmarked, int M) {
    int m = blockIdx.x * blockDim.x + threadIdx.x;
    if (m < M) {
        int n = nidx[m];
        if (atomicExch(&mark[n], 1) == 0) list[atomicAdd(nmarked, 1)] = n;
    }
}

// ---------------- conversions ----------------

__global__ void k_tobf16(const float* __restrict__ in, unsigned short* __restrict__ out, int n4) {
    int i = blockIdx.x * blockDim.x + threadIdx.x;
    int stride = gridDim.x * blockDim.x;
    for (; i < n4; i += stride) {
        float4 v = ((const float4*)in)[i];
        ushort4 u;
        u.x = f2b(v.x); u.y = f2b(v.y); u.z = f2b(v.z); u.w = f2b(v.w);
        ((ushort4*)out)[i] = u;
    }
}

// all six weight matrices -> one bf16 buffer
// offsets: W1l 0, W1r 16384, W2l 32768, W2r 49152, fcW1 65536, fcW2 81920 (total 90112)
__global__ void k_wconv(const float* __restrict__ W1l, const float* __restrict__ W1r,
                        const float* __restrict__ W2l, const float* __restrict__ W2r,
                        const float* __restrict__ fcW1, const float* __restrict__ fcW2,
                        unsigned short* __restrict__ Wb) {
    int i = blockIdx.x * blockDim.x + threadIdx.x;
    if (i >= 90112) return;
    float v;
    if (i < 16384) v = W1l[i];
    else if (i < 32768) v = W1r[i - 16384];
    else if (i < 49152) v = W2l[i - 32768];
    else if (i < 65536) v = W2r[i - 49152];
    else if (i < 81920) v = fcW1[i - 65536];
    else v = fcW2[i - 81920];
    Wb[i] = f2b(v);
}

// ---------------- aggregation (bf16 feat): wave per dst node, fused mean ----------------
__global__ void k_aggr_b(const int* __restrict__ rowptr, const int* __restrict__ srclist,
                         const unsigned int* __restrict__ feat, const float* __restrict__ invc,
                         const int* __restrict__ list, const int* __restrict__ nlist,
                         unsigned int* __restrict__ outf, int n) {
    int lane = threadIdx.x & 63;
    int w = blockIdx.x * (blockDim.x >> 6) + (threadIdx.x >> 6);
    int node;
    if (list) {
        int nm = *nlist;
        if (w >= nm) return;
        node = list[w];
    } else {
        if (w >= n) return;
        node = w;
    }
    int beg = rowptr[node], end = rowptr[node + 1];
    float a0 = 0.f, a1 = 0.f;
    int i = beg;
    for (; i + 4 <= end; i += 4) {
        unsigned u0 = feat[(size_t)srclist[i] * 64 + lane];
        unsigned u1 = feat[(size_t)srclist[i + 1] * 64 + lane];
        unsigned u2 = feat[(size_t)srclist[i + 2] * 64 + lane];
        unsigned u3 = feat[(size_t)srclist[i + 3] * 64 + lane];
        a0 += __uint_as_float(u0 << 16) + __uint_as_float(u1 << 16) +
              __uint_as_float(u2 << 16) + __uint_as_float(u3 << 16);
        a1 += __uint_as_float(u0 & 0xffff0000u) + __uint_as_float(u1 & 0xffff0000u) +
              __uint_as_float(u2 & 0xffff0000u) + __uint_as_float(u3 & 0xffff0000u);
    }
    for (; i < end; i++) {
        unsigned u = feat[(size_t)srclist[i] * 64 + lane];
        a0 += __uint_as_float(u << 16);
        a1 += __uint_as_float(u & 0xffff0000u);
    }
    float ic = invc[node];
    a0 *= ic; a1 *= ic;
    outf[(size_t)node * 64 + lane] = ((unsigned)f2b(a1) << 16) | (unsigned)f2b(a0);
}

// ---------------- MFMA dense: out = A@Wl.T (+ X@Wr.T) + b ----------------
// bf16 operands, fp32 accum. LDS-free: fragments load directly from global
// (perfectly coalesced 16-line dwordx4 per fragment). 4 waves/block, 32 rows/wave
// (2 MFMA row-subtiles sharing B frags). REQUIRES nrows % 32 == 0.
template <int NCT, int TWO, int RELU, int OUTBF>
__global__ void k_mdense(const unsigned short* __restrict__ A,
                         const unsigned short* __restrict__ X,
                         const int* __restrict__ gidx,
                         const unsigned short* __restrict__ Wl,
                         const float* __restrict__ bl,
                         const unsigned short* __restrict__ Wr,
                         void* __restrict__ outp, int nrows) {
    const int OC = NCT * 16;
    int lane = threadIdx.x & 63;
    int wave = threadIdx.x >> 6;
    int rowBase = (blockIdx.x * 4 + wave) * 32;
    if (rowBase >= nrows) return;
    int rl = lane & 15;   // A row / B col within tile
    int ks = lane >> 4;   // k-subgroup (8 bf16 each)
    int r0 = rowBase + rl, r1 = r0 + 16;
    int n0 = gidx ? gidx[r0] : r0;
    int n1 = gidx ? gidx[r1] : r1;
    f32x4 acc0[NCT], acc1[NCT];
#pragma unroll
    for (int ct = 0; ct < NCT; ct++) {
        acc0[ct] = (f32x4)0.f;
        acc1[ct] = (f32x4)0.f;
    }
#pragma unroll
    for (int pass = 0; pass < (TWO ? 2 : 1); pass++) {
        const unsigned short* Ain = pass ? X : A;
        const unsigned short* W = pass ? Wr : Wl;
        const s16x8* a0p = (const s16x8*)(Ain + (size_t)n0 * 128);
        const s16x8* a1p = (const s16x8*)(Ain + (size_t)n1 * 128);
#pragma unroll
        for (int kc = 0; kc < 4; kc++) {
            s16x8 af0 = a0p[kc * 4 + ks];
            s16x8 af1 = a1p[kc * 4 + ks];
#pragma unroll
            for (int ct = 0; ct < NCT; ct++) {
                const s16x8* bp = (const s16x8*)(W + (size_t)(ct * 16 + rl) * 128);
                s16x8 bf = bp[kc * 4 + ks];
                acc0[ct] = __builtin_amdgcn_mfma_f32_16x16x32_bf16(af0, bf, acc0[ct], 0, 0, 0);
                acc1[ct] = __builtin_amdgcn_mfma_f32_16x16x32_bf16(af1, bf, acc1[ct], 0, 0, 0);
            }
        }
    }
    // D layout: lane holds D[(lane>>4)*4 + j][lane&15]
#pragma unroll
    for (int ct = 0; ct < NCT; ct++) {
        int col = ct * 16 + rl;
        float bj = bl[col];
#pragma unroll
        for (int j = 0; j < 4; j++) {
            int or0 = rowBase + ks * 4 + j;
            int or1 = or0 + 16;
            float v0 = acc0[ct][j] + bj;
            float v1 = acc1[ct][j] + bj;
            if (RELU) { v0 = fmaxf(v0, 0.f); v1 = fmaxf(v1, 0.f); }
            if (OUTBF) {
                ((unsigned short*)outp)[(size_t)or0 * OC + col] = f2b(v0);
                ((unsigned short*)outp)[(size_t)or1 * OC + col] = f2b(v1);
            } else {
                ((float*)outp)[(size_t)or0 * OC + col] = v0;
                ((float*)outp)[(size_t)or1 * OC + col] = v1;
            }
        }
    }
}

// ---------------- batchnorm ----------------
template <int C>
__global__ void k_bnstats(const float* __restrict__ z, float* __restrict__ gsum,
                          float* __restrict__ gsq, int nrows, int rowsPerBlock) {
    int t = threadIdx.x;
    int c = t % C;
    int g = t / C;
    const int G = 256 / C;
    int r0 = blockIdx.x * rowsPerBlock;
    int r1 = min(r0 + rowsPerBlock, nrows);
    float s = 0.f, q = 0.f;
    for (int r = r0 + g; r < r1; r += G) {
        float v = z[(size_t)r * C + c];
        s += v;
        q += v * v;
    }
    __shared__ float ls[256], lq[256];
    ls[t] = s;
    lq[t] = q;
    __syncthreads();
    if (t < C) {
        for (int g2 = 1; g2 < G; g2++) {
            s += ls[g2 * C + c];
            q += lq[g2 * C + c];
        }
        atomicAdd(&gsum[c], s);
        atomicAdd(&gsq[c], q);
    }
}

__global__ void k_bnprep(const float* __restrict__ gsum, const float* __restrict__ gsq,
                         const float* __restrict__ gamma, const float* __restrict__ beta,
                         float* __restrict__ scale, float* __restrict__ shift, int C, float invM) {
    int c = blockIdx.x * blockDim.x + threadIdx.x;
    if (c < C) {
        float mean = gsum[c] * invM;
        float var = gsq[c] * invM - mean * mean;
        float is = rsqrtf(var + EPSV);
        float sc = gamma[c] * is;
        scale[c] = sc;
        shift[c] = beta[c] - mean * sc;
    }
}

template <int OUTBF>
__global__ void k_bn_act(const float* __restrict__ z, const float* __restrict__ scale,
                         const float* __restrict__ shift, void* __restrict__ outp,
                         int total, int colsMask, float slope) {
    int i = blockIdx.x * blockDim.x + threadIdx.x;
    if (i < total) {
        int c = i & colsMask;
        float y = z[i] * scale[c] + shift[c];
        y = (y >= 0.f) ? y : slope * y;
        if (OUTBF) ((unsigned short*)outp)[i] = f2b(y);
        else ((float*)outp)[i] = y;
    }
}

// ---------------- final fc3: wave per row ----------------
__global__ void k_fc3(const float* __restrict__ z2, const float* __restrict__ w,
                      const float* __restrict__ b, float* __restrict__ out, int nrows) {
    int lane = threadIdx.x & 63;
    int m = blockIdx.x * (blockDim.x >> 6) + (threadIdx.x >> 6);
    if (m >= nrows) return;
    float v = z2[(size_t)m * 64 + lane] * w[lane];
    for (int off = 32; off > 0; off >>= 1) v += __shfl_down(v, off);
    if (lane == 0) out[m] = v + b[0];
}

// ---------------- launch ----------------
extern "C" void kernel_launch(void* const* d_in, const int* in_sizes, int n_in,
                              void* d_out, int out_size, void* d_ws, size_t ws_size,
                              hipStream_t stream) {
    const float* x    = (const float*)d_in[0];
    const int*   ei   = (const int*)d_in[1];
    const int*   nidx = (const int*)d_in[2];
    const float* W1l  = (const float*)d_in[3];
    const float* b1   = (const float*)d_in[4];
    const float* W1r  = (const float*)d_in[5];
    const float* W2l  = (const float*)d_in[6];
    const float* b2   = (const float*)d_in[7];
    const float* W2r  = (const float*)d_in[8];
    const float* fcW1 = (const float*)d_in[9];
    const float* fcb1 = (const float*)d_in[10];
    const float* fcW2 = (const float*)d_in[11];
    const float* fcb2 = (const float*)d_in[12];
    const float* fcW3 = (const float*)d_in[13];
    const float* fcb3 = (const float*)d_in[14];
    const float* g1   = (const float*)d_in[15];
    const float* be1  = (const float*)d_in[16];
    const float* g2   = (const float*)d_in[17];
    const float* be2  = (const float*)d_in[18];

    const int N = in_sizes[0] / 128;
    const int E = in_sizes[1] / 2;
    const int M = in_sizes[2];
    const int* src = ei;
    const int* dst = ei + E;
    const int B = (N + SEG - 1) / SEG;

    char* ws = (char*)d_ws;
    size_t off = 0;
    unsigned short* xb  = (unsigned short*)(ws + off); off += (size_t)N * 128 * 2;
    unsigned short* sb  = (unsigned short*)(ws + off); off += (size_t)N * 128 * 2;
    unsigned short* h1b = (unsigned short*)(ws + off); off += (size_t)N * 128 * 2;
    unsigned short* z0b = (unsigned short*)(ws + off); off += (size_t)M * 128 * 2;
    float* z1           = (float*)(ws + off);          off += (size_t)M * 128 * 4;
    unsigned short* z1b = (unsigned short*)(ws + off); off += (size_t)M * 128 * 2;
    float* z2           = (float*)(ws + off);          off += (size_t)M * 64 * 4;
    unsigned short* Wb  = (unsigned short*)(ws + off); off += 90112 * 2;
    int*   cnt     = (int*)(ws + off);   off += (size_t)N * 4;
    float* invc    = (float*)(ws + off); off += (size_t)N * 4;
    int*   mark    = (int*)(ws + off);   off += (size_t)N * 4;
    int*   rowptr  = (int*)(ws + off);   off += (size_t)(N + 1) * 4;
    int*   cursor  = (int*)(ws + off);   off += (size_t)N * 4;
    int*   srclist = (int*)(ws + off);   off += (size_t)E * 4;
    int*   list    = (int*)(ws + off);   off += (size_t)M * 4;
    int*   bsum    = (int*)(ws + off);   off += 256 * 4;
    int*   nmarked = (int*)(ws + off);   off += 64;
    float* gsum1   = (float*)(ws + off); off += 128 * 4;
    float* gsq1    = (float*)(ws + off); off += 128 * 4;
    float* scale1  = (float*)(ws + off); off += 128 * 4;
    float* shift1  = (float*)(ws + off); off += 128 * 4;
    float* gsum2   = (float*)(ws + off); off += 64 * 4;
    float* gsq2    = (float*)(ws + off); off += 64 * 4;
    float* scale2  = (float*)(ws + off); off += 64 * 4;
    float* shift2  = (float*)(ws + off); off += 64 * 4;
    float* out = (float*)d_out;

    hipMemsetAsync(cnt, 0, (size_t)N * 4, stream);
    hipMemsetAsync(mark, 0, (size_t)N * 4, stream);
    hipMemsetAsync(nmarked, 0, 4, stream);
    hipMemsetAsync(gsum1, 0, (128 + 128 + 128 + 128 + 64 + 64 + 64 + 64) * 4, stream);

    // conversions (independent of CSR build)
    k_wconv<<<(90112 + 255) / 256, 256, 0, stream>>>(W1l, W1r, W2l, W2r, fcW1, fcW2, Wb);
    k_tobf16<<<2048, 256, 0, stream>>>(x, xb, N * 128 / 4);

    // CSR build
    k_count_i<<<(E + 255) / 256, 256, 0, stream>>>(dst, cnt, E);
    k_bsum<<<B, 256, 0, stream>>>(cnt, bsum, N);
    k_scanb<<<1, 256, 0, stream>>>(bsum, B);
    k_scanseg<<<B, 256, 0, stream>>>(cnt, bsum, rowptr, cursor, invc, N, B);
    k_fill<<<(E + 255) / 256, 256, 0, stream>>>(src, dst, cursor, srclist, E);
    k_mark<<<(M + 255) / 256, 256, 0, stream>>>(nidx, mark, list, nmarked, M);

    // layer 1
    k_aggr_b<<<(N + 3) / 4, 256, 0, stream>>>(rowptr, srclist, (const unsigned int*)xb, invc,
                                              nullptr, nullptr, (unsigned int*)sb, N);
    k_mdense<8, 1, 1, 1><<<(N / 32 + 3) / 4, 256, 0, stream>>>(
        sb, xb, nullptr, Wb + 0, b1, Wb + 16384, h1b, N);

    // layer 2 (only marked dst nodes)
    k_aggr_b<<<(M + 3) / 4, 256, 0, stream>>>(rowptr, srclist, (const unsigned int*)h1b, invc,
                                              list, nmarked, (unsigned int*)sb, N);
    k_mdense<8, 1, 0, 1><<<(M / 32 + 3) / 4, 256, 0, stream>>>(
        sb, h1b, nidx, Wb + 32768, b2, Wb + 49152, z0b, M);

    // MLP head
    k_mdense<8, 0, 0, 0><<<(M / 32 + 3) / 4, 256, 0, stream>>>(
        z0b, nullptr, nullptr, Wb + 65536, fcb1, nullptr, z1, M);
    k_bnstats<128><<<(M + 99) / 100, 256, 0, stream>>>(z1, gsum1, gsq1, M, 100);
    k_bnprep<<<1, 128, 0, stream>>>(gsum1, gsq1, g1, be1, scale1, shift1, 128, 1.0f / M);
    k_bn_act<1><<<((size_t)M * 128 + 255) / 256, 256, 0, stream>>>(
        z1, scale1, shift1, z1b, M * 128, 127, 0.1f);

    k_mdense<4, 0, 0, 0><<<(M / 32 + 3) / 4, 256, 0, stream>>>(
        z1b, nullptr, nullptr, Wb + 81920, fcb2, nullptr, z2, M);
    k_bnstats<64><<<(M + 99) / 100, 256, 0, stream>>>(z2, gsum2, gsq2, M, 100);
    k_bnprep<<<1, 64, 0, stream>>>(gsum2, gsq2, g2, be2, scale2, shift2, 64, 1.0f / M);
    k_bn_act<0><<<((size_t)M * 64 + 255) / 256, 256, 0, stream>>>(
        z2, scale2, shift2, z2, M * 64, 63, 0.05f);

    k_fc3<<<(M + 3) / 4, 256, 0, stream>>>(z2, fcW3, fcb3, out, M);
}